// Round 8
// baseline (243.802 us; speedup 1.0000x reference)
//
#include <hip/hip_runtime.h>
#include <hip/hip_bf16.h>
#include <math.h>

// Shapes: B=1, M=2, L=256, D=256, D2=512, S=128.
// xp row convention: r = t*512 + m*256 + l  (t: 0=x, 1=mouth), 512 cols.

#define D_   256
#define D2_  512
#define S_   128

__device__ __forceinline__ float silu_f(float v) {
    return v / (1.f + __expf(-v));
}
__device__ __forceinline__ float softplus_f(float v) {
    return fmaxf(v, 0.f) + log1pf(__expf(-fabsf(v)));
}

// ================= K1: fused rmsnorm + inp GEMM -> xp [1024][512] =================
// 32x64 tile, 256 threads, K=256 (8 chunks of 32). In-block per-row inv-RMS:
// each row is staged by 8 threads (j=t&7) which also compute sum(x^2) via shfl.
__global__ __launch_bounds__(256) void gemm_norm_k(
        const float* __restrict__ x, const float* __restrict__ mouth,
        const float* __restrict__ nw,
        const float* __restrict__ W, const float* __restrict__ bias,
        float* __restrict__ O) {
    __shared__ float As[2][32][36];
    __shared__ float Ws[2][32][68];
    const int rt = blockIdx.x >> 3;       // 0..31
    const int ct = blockIdx.x & 7;        // 0..7
    const int r0 = rt * 32, c0 = ct * 64;
    const int t  = threadIdx.x;
    const int sr = t >> 3;                // 0..31
    const int sk = (t & 7) << 2;          // 0..28
    const int rowA = r0 + sr;
    const float* rowbase = (rowA < 512) ? (x + (size_t)rowA * 256)
                                        : (mouth + (size_t)(rowA - 512) * 256);
    // in-block inverse RMS for this row (8 cooperating threads j = t&7)
    const int j = t & 7;
    float ssum = 0.f;
    const float* rp = rowbase + j * 32;
#pragma unroll
    for (int q = 0; q < 8; ++q) {
        float4 v = *(const float4*)(rp + q * 4);
        ssum += v.x * v.x + v.y * v.y + v.z * v.z + v.w * v.w;
    }
    ssum += __shfl_xor(ssum, 1);
    ssum += __shfl_xor(ssum, 2);
    ssum += __shfl_xor(ssum, 4);
    const float ascale = 1.f / sqrtf(ssum + 1e-5f);

    const float* Abase  = rowbase + sk;
    const float* W1base = W + (size_t)(c0 + sr) * 256 + sk;
    const float* W2base = W + (size_t)(c0 + 32 + sr) * 256 + sk;
    float4 areg  = *(const float4*)Abase;
    float4 w1reg = *(const float4*)W1base;
    float4 w2reg = *(const float4*)W2base;
    float4 nwreg = *(const float4*)(nw + sk);
    const int tr = (t >> 5) << 2;         // 0..28
    const int tc = (t & 31) << 1;         // 0..62
    float acc[4][2] = {};
    for (int ch = 0; ch < 8; ++ch) {
        const int p = ch & 1;
        float4 a = areg;
        a.x *= ascale * nwreg.x; a.y *= ascale * nwreg.y;
        a.z *= ascale * nwreg.z; a.w *= ascale * nwreg.w;
        As[p][sk + 0][sr] = a.x;  As[p][sk + 1][sr] = a.y;
        As[p][sk + 2][sr] = a.z;  As[p][sk + 3][sr] = a.w;
        Ws[p][sk + 0][sr] = w1reg.x;  Ws[p][sk + 1][sr] = w1reg.y;
        Ws[p][sk + 2][sr] = w1reg.z;  Ws[p][sk + 3][sr] = w1reg.w;
        Ws[p][sk + 0][sr + 32] = w2reg.x;  Ws[p][sk + 1][sr + 32] = w2reg.y;
        Ws[p][sk + 2][sr + 32] = w2reg.z;  Ws[p][sk + 3][sr + 32] = w2reg.w;
        __syncthreads();
        if (ch < 7) {
            const int ko = (ch + 1) << 5;
            areg  = *(const float4*)(Abase + ko);
            w1reg = *(const float4*)(W1base + ko);
            w2reg = *(const float4*)(W2base + ko);
            nwreg = *(const float4*)(nw + ko + sk);
        }
#pragma unroll
        for (int kk = 0; kk < 32; ++kk) {
            const float4 a4 = *(const float4*)&As[p][kk][tr];
            const float2 w2 = *(const float2*)&Ws[p][kk][tc];
            acc[0][0] = fmaf(a4.x, w2.x, acc[0][0]); acc[0][1] = fmaf(a4.x, w2.y, acc[0][1]);
            acc[1][0] = fmaf(a4.y, w2.x, acc[1][0]); acc[1][1] = fmaf(a4.y, w2.y, acc[1][1]);
            acc[2][0] = fmaf(a4.z, w2.x, acc[2][0]); acc[2][1] = fmaf(a4.z, w2.y, acc[2][1]);
            acc[3][0] = fmaf(a4.w, w2.x, acc[3][0]); acc[3][1] = fmaf(a4.w, w2.y, acc[3][1]);
        }
    }
    const float2 bv = *(const float2*)(bias + c0 + tc);
#pragma unroll
    for (int i = 0; i < 4; ++i) {
        *(float2*)(O + (size_t)(r0 + tr + i) * 512 + c0 + tc) =
            make_float2(acc[i][0] + bv.x, acc[i][1] + bv.y);
    }
}

// ================= K2: conv + fc1 + fc2 + ssm + res(Dlin) + combine + out =================
// One block per (m, l-pair): 256 blocks x 512 threads. All downstream stages are
// row-local in (m,l) given the xp l-halo. Weight rows laid out so <=256 distinct
// rows are streamed at once (L1-resident dedup across thread halves).
__global__ __launch_bounds__(512) void mega_k(
        const float* __restrict__ xp, const float* __restrict__ x,
        const float* __restrict__ nw,
        const float* __restrict__ convW, const float* __restrict__ convB,
        const float* __restrict__ fc1W, const float* __restrict__ fc1b,
        const float* __restrict__ fc2W, const float* __restrict__ fc2b,
        const float* __restrict__ DW,   const float* __restrict__ Db,
        const float* __restrict__ A,    const float* __restrict__ outW,
        const float* __restrict__ outb, float* __restrict__ out) {
    __shared__ float xph[2][2][4][512];   // [t][i][hslot][w], hslot h -> l = l0-1+h (32KB)
    __shared__ float xcs[2][2][512];      // conv+silu outputs [t][lr][w]            (8KB)
    __shared__ float xns[2][256];         // rmsnormed x rows (t=0, ch=m) for res    (2KB)
    __shared__ float deltas[2][2][512];   // softplus(fc1) [t][lr][d]                (8KB)
    __shared__ float Bms[2][2][128];      // fc2 outputs [t][lr][n]                  (2KB)
    __shared__ float combs[2][512];       // (silu(ssm_x)+silu(ssm_m))*res           (4KB)
    __shared__ float red[8];
    const int tid = threadIdx.x;
    const int m  = blockIdx.x >> 7;             // 0..1
    const int l0 = (blockIdx.x & 127) << 1;     // 0,2,..,254

    // ---- A: load xp halo rows l0-1 .. l0+2 for t=0,1 and i=0,1 (zeros outside) ----
#pragma unroll
    for (int jj = 0; jj < 4; ++jj) {
        int f   = tid + jj * 512;               // 0..2047 float4 slots
        int w4  = f & 127;
        int row = f >> 7;                       // 0..15
        int tt = row >> 3, ii = (row >> 2) & 1, h = row & 3;
        int l = l0 - 1 + h;
        float4 v = make_float4(0.f, 0.f, 0.f, 0.f);
        if (l >= 0 && l <= 255)
            v = *(const float4*)(xp + (size_t)(tt * 512 + ii * 256 + l) * 512 + w4 * 4);
        *(float4*)&xph[tt][ii][h][w4 * 4] = v;
    }
    // ---- C: rmsnormed x rows (for res); reduce via shfl + red[] ----
    {
        int lr = tid >> 8, c = tid & 255;
        float v = x[(size_t)(m * 256 + l0 + lr) * 256 + c];
        float sq = v * v;
        for (int off = 32; off; off >>= 1) sq += __shfl_xor(sq, off);
        if ((tid & 63) == 0) red[tid >> 6] = sq;
        __syncthreads();                                        // bar1 (xph + red ready)
        float invr = 1.f / sqrtf(red[lr * 4] + red[lr * 4 + 1] +
                                 red[lr * 4 + 2] + red[lr * 4 + 3] + 1e-5f);
        xns[lr][c] = v * invr * nw[c];
    }
    // ---- B: conv3x3 (channels i=0,1 -> o=m) + bias + silu ----
    {
        const int w = tid;                      // 0..511
        float cw[2][3][3];
#pragma unroll
        for (int ii = 0; ii < 2; ++ii)
#pragma unroll
            for (int dh = 0; dh < 3; ++dh)
#pragma unroll
                for (int dw = 0; dw < 3; ++dw)
                    cw[ii][dh][dw] = convW[((m * 2 + ii) * 3 + dh) * 3 + dw];
        const float cb = convB[m];
#pragma unroll
        for (int tt = 0; tt < 2; ++tt)
#pragma unroll
            for (int lr = 0; lr < 2; ++lr) {
                float acc = cb;
#pragma unroll
                for (int ii = 0; ii < 2; ++ii)
#pragma unroll
                    for (int dh = 0; dh < 3; ++dh) {
                        const float* src = &xph[tt][ii][lr + dh][0];
                        if (w >= 1)   acc += src[w - 1] * cw[ii][dh][0];
                                      acc += src[w    ] * cw[ii][dh][1];
                        if (w <= 510) acc += src[w + 1] * cw[ii][dh][2];
                    }
                xcs[tt][lr][w] = silu_f(acc);
            }
    }
    __syncthreads();                                            // bar2 (xcs ready)
    // ---- D: fc1 -> softplus -> deltas. 2 passes of 256 d-rows; t-halves share rows ----
    {
        const int rep = tid >> 8;               // = t
        const int dd  = tid & 255;
        for (int pass = 0; pass < 2; ++pass) {
            const int d = pass * 256 + dd;
            const float4* wrow = (const float4*)(fc1W + (size_t)d * 512);
            float a0 = 0.f, a1 = 0.f;
            for (int k4 = 0; k4 < 128; ++k4) {
                float4 w4 = wrow[k4]; int k = k4 * 4;
                a0 += w4.x * xcs[rep][0][k] + w4.y * xcs[rep][0][k + 1]
                    + w4.z * xcs[rep][0][k + 2] + w4.w * xcs[rep][0][k + 3];
                a1 += w4.x * xcs[rep][1][k] + w4.y * xcs[rep][1][k + 1]
                    + w4.z * xcs[rep][1][k + 2] + w4.w * xcs[rep][1][k + 3];
            }
            const float b = fc1b[d];
            deltas[rep][0][d] = softplus_f(a0 + b);
            deltas[rep][1][d] = softplus_f(a1 + b);
        }
    }
    // ---- E: fc2 -> Bms; per-(t,lr) sum(Bm^2) partials into red[] ----
    {
        const int g = tid >> 7;                 // 0..3: t=g>>1, lr=g&1
        const int n = tid & 127;
        const int tt = g >> 1, lr = g & 1;
        const float4* wrow = (const float4*)(fc2W + (size_t)n * 512);
        float acc = 0.f;
        for (int k4 = 0; k4 < 128; ++k4) {
            float4 w4 = wrow[k4]; int k = k4 * 4;
            acc += w4.x * xcs[tt][lr][k] + w4.y * xcs[tt][lr][k + 1]
                 + w4.z * xcs[tt][lr][k + 2] + w4.w * xcs[tt][lr][k + 3];
        }
        acc += fc2b[n];
        Bms[tt][lr][n] = acc;
        float sq = acc * acc;
        for (int off = 32; off; off >>= 1) sq += __shfl_xor(sq, off);
        if ((tid & 63) == 0) red[tid >> 6] = sq;    // s2(t,lr) = red[2g]+red[2g+1]
    }
    // ---- F: res = silu(Dlin(xn)) -> regs ----
    float resv0, resv1;
    {
        const int d = tid;
        const float4* wrow = (const float4*)(DW + (size_t)d * 256);
        float a0 = 0.f, a1 = 0.f;
        for (int k4 = 0; k4 < 64; ++k4) {
            float4 w4 = wrow[k4]; int k = k4 * 4;
            a0 += w4.x * xns[0][k] + w4.y * xns[0][k + 1]
                + w4.z * xns[0][k + 2] + w4.w * xns[0][k + 3];
            a1 += w4.x * xns[1][k] + w4.y * xns[1][k + 1]
                + w4.z * xns[1][k + 2] + w4.w * xns[1][k + 3];
        }
        const float b = Db[d];
        resv0 = silu_f(a0 + b);
        resv1 = silu_f(a1 + b);
    }
    __syncthreads();                                            // bar3 (deltas,Bms,red)
    // ---- G: ssm + silu + combine ----
    {
        const int d = tid;
        float s2[2][2];
#pragma unroll
        for (int g = 0; g < 4; ++g) s2[g >> 1][g & 1] = red[2 * g] + red[2 * g + 1];
        float dl[2][2];
        dl[0][0] = deltas[0][0][d]; dl[0][1] = deltas[0][1][d];
        dl[1][0] = deltas[1][0][d]; dl[1][1] = deltas[1][1][d];
        float accs[2][2] = {};
        const float4* arow = (const float4*)(A + (size_t)d * 128);
        for (int k4 = 0; k4 < 32; ++k4) {
            float4 a4 = arow[k4];
            const int n = k4 * 4;
#pragma unroll
            for (int cmp = 0; cmp < 4; ++cmp) {
                float a = (cmp == 0) ? a4.x : (cmp == 1) ? a4.y : (cmp == 2) ? a4.z : a4.w;
#pragma unroll
                for (int tt = 0; tt < 2; ++tt)
#pragma unroll
                    for (int lr = 0; lr < 2; ++lr)
                        accs[tt][lr] += Bms[tt][lr][n + cmp] * __expf(dl[tt][lr] * a);
            }
        }
        float ssm[2][2];
#pragma unroll
        for (int tt = 0; tt < 2; ++tt)
#pragma unroll
            for (int lr = 0; lr < 2; ++lr)
                ssm[tt][lr] = accs[tt][lr] + xcs[tt][lr][d] * dl[tt][lr] * s2[tt][lr];
        combs[0][d] = (silu_f(ssm[0][0]) + silu_f(ssm[1][0])) * resv0;
        combs[1][d] = (silu_f(ssm[0][1]) + silu_f(ssm[1][1])) * resv1;
    }
    __syncthreads();                                            // bar4 (combs ready)
    // ---- H: out = comb @ out_W^T + out_b ----
    {
        const int lr = tid >> 8, c = tid & 255;
        const float4* wrow = (const float4*)(outW + (size_t)c * 512);
        float acc = outb[c];
        for (int k4 = 0; k4 < 128; ++k4) {
            float4 w4 = wrow[k4]; int k = k4 * 4;
            acc += w4.x * combs[lr][k] + w4.y * combs[lr][k + 1]
                 + w4.z * combs[lr][k + 2] + w4.w * combs[lr][k + 3];
        }
        out[(size_t)(m * 256 + l0 + lr) * 256 + c] = acc;
    }
}

extern "C" void kernel_launch(void* const* d_in, const int* in_sizes, int n_in,
                              void* d_out, int out_size, void* d_ws, size_t ws_size,
                              hipStream_t stream) {
    const float* x      = (const float*)d_in[0];
    const float* mouth  = (const float*)d_in[1];
    const float* norm_w = (const float*)d_in[2];
    const float* inp_W  = (const float*)d_in[3];
    const float* inp_b  = (const float*)d_in[4];
    const float* out_W  = (const float*)d_in[5];
    const float* out_b  = (const float*)d_in[6];
    const float* Dlin_W = (const float*)d_in[7];
    const float* Dlin_b = (const float*)d_in[8];
    const float* conv_W = (const float*)d_in[9];
    const float* conv_b = (const float*)d_in[10];
    const float* fc1_W  = (const float*)d_in[11];
    const float* fc1_b  = (const float*)d_in[12];
    const float* fc2_W  = (const float*)d_in[13];
    const float* fc2_b  = (const float*)d_in[14];
    const float* A      = (const float*)d_in[15];

    float* xp  = (float*)d_ws;     // 1024 x 512
    float* out = (float*)d_out;

    // K1: xp = rmsnorm(x|mouth) @ inp_W^T + inp_b   (1024x512, K=256)
    gemm_norm_k<<<256, 256, 0, stream>>>(x, mouth, norm_w, inp_W, inp_b, xp);
    // K2: conv -> fc1/fc2 -> ssm -> res -> combine -> out  (row-local mega kernel)
    mega_k<<<256, 512, 0, stream>>>(xp, x, norm_w, conv_W, conv_b,
                                    fc1_W, fc1_b, fc2_W, fc2_b,
                                    Dlin_W, Dlin_b, A, out_W, out_b, out);
}

// Round 10
// 161.083 us; speedup vs baseline: 1.5135x; 1.5135x over previous
//
#include <hip/hip_runtime.h>
#include <hip/hip_bf16.h>
#include <math.h>

// Shapes: B=1, M=2, L=256, D=256, D2=512, S=128.
// Row convention: r = t*512 + (m*256 + l), t in {0(x),1(mouth)}.

#define D_   256
#define D2_  512
#define S_   128

__device__ __forceinline__ float silu_f(float v) {
    return v / (1.f + __expf(-v));
}
__device__ __forceinline__ float softplus_f(float v) {
    return fmaxf(v, 0.f) + log1pf(__expf(-fabsf(v)));
}

// ---- dual-output tiled GEMM: tile 32(M) x 64(N), 256 threads, KC=32 ----
// blocks [0,n1): O1 = act1(A@W1^T + b1); blocks [n1,..): O2 = act2(A@W2^T + b2).
// NORM: A rows are rmsnorm'ed in-block (K must be 256): 8 threads per row
// compute sum(x^2) via shfl, A scaled by invr*nw[k] during staging.
// A rows >= 512 come from A1. k-major LDS with pad -> clean vector reads.
// One __syncthreads per chunk; double-buffered (store ch -> barrier ->
// prefetch ch+1 -> compute ch); safe: stores to buffer p at ch+2 follow
// barrier(ch+1) which follows compute(ch).
template<bool NORM, int ACT1, int ACT2>
__global__ __launch_bounds__(256) void gemm_dual_k(
        const float* __restrict__ A0, const float* __restrict__ A1,
        const float* __restrict__ nw,
        const float* __restrict__ W1, const float* __restrict__ bias1,
        float* __restrict__ O1, int nct1, int ldo1, int n1,
        const float* __restrict__ W2, const float* __restrict__ bias2,
        float* __restrict__ O2, int nct2, int ldo2, int K) {
    __shared__ float As[2][32][36];
    __shared__ float Ws[2][32][68];
    const int b = blockIdx.x;
    const float *W, *bias; float* O; int ldo, act, rt, ct;
    if (b < n1) { W = W1; bias = bias1; O = O1; ldo = ldo1; act = ACT1; rt = b / nct1; ct = b % nct1; }
    else { int bb = b - n1; W = W2; bias = bias2; O = O2; ldo = ldo2; act = ACT2; rt = bb / nct2; ct = bb % nct2; }
    const int r0 = rt * 32, c0 = ct * 64;
    const int t = threadIdx.x;
    const int sr = t >> 3;                // 0..31
    const int sk = (t & 7) << 2;          // 0..28
    const int rowA = r0 + sr;
    const float* rowbase = (rowA < 512) ? (A0 + (size_t)rowA * K)
                                        : (A1 + (size_t)(rowA - 512) * K);
    float ascale = 1.f;
    if (NORM) {   // K == 256: 8 lanes (j=t&7) cooperate on this row's sum(x^2)
        const int j = t & 7;
        float ssum = 0.f;
        const float* rp = rowbase + j * 32;
#pragma unroll
        for (int q = 0; q < 8; ++q) {
            float4 v = *(const float4*)(rp + q * 4);
            ssum += v.x * v.x + v.y * v.y + v.z * v.z + v.w * v.w;
        }
        ssum += __shfl_xor(ssum, 1);
        ssum += __shfl_xor(ssum, 2);
        ssum += __shfl_xor(ssum, 4);
        ascale = 1.f / sqrtf(ssum + 1e-5f);
    }
    const float* Abase  = rowbase + sk;
    const float* W1base = W + (size_t)(c0 + sr) * K + sk;
    const float* W2base = W + (size_t)(c0 + 32 + sr) * K + sk;
    float4 areg  = *(const float4*)Abase;
    float4 w1reg = *(const float4*)W1base;
    float4 w2reg = *(const float4*)W2base;
    float4 nwreg = NORM ? *(const float4*)(nw + sk) : make_float4(0.f, 0.f, 0.f, 0.f);
    const int tr = (t >> 5) << 2;         // 0..28
    const int tc = (t & 31) << 1;         // 0..62
    float acc[4][2] = {};
    const int nch = K >> 5;
    for (int ch = 0; ch < nch; ++ch) {
        const int p = ch & 1;
        float4 a = areg;
        if (NORM) {
            a.x *= ascale * nwreg.x; a.y *= ascale * nwreg.y;
            a.z *= ascale * nwreg.z; a.w *= ascale * nwreg.w;
        }
        As[p][sk + 0][sr] = a.x;  As[p][sk + 1][sr] = a.y;
        As[p][sk + 2][sr] = a.z;  As[p][sk + 3][sr] = a.w;
        Ws[p][sk + 0][sr] = w1reg.x;  Ws[p][sk + 1][sr] = w1reg.y;
        Ws[p][sk + 2][sr] = w1reg.z;  Ws[p][sk + 3][sr] = w1reg.w;
        Ws[p][sk + 0][sr + 32] = w2reg.x;  Ws[p][sk + 1][sr + 32] = w2reg.y;
        Ws[p][sk + 2][sr + 32] = w2reg.z;  Ws[p][sk + 3][sr + 32] = w2reg.w;
        __syncthreads();
        if (ch + 1 < nch) {
            const int ko = (ch + 1) << 5;
            areg  = *(const float4*)(Abase + ko);
            w1reg = *(const float4*)(W1base + ko);
            w2reg = *(const float4*)(W2base + ko);
            if (NORM) nwreg = *(const float4*)(nw + ko + sk);
        }
#pragma unroll
        for (int kk = 0; kk < 32; ++kk) {
            const float4 a4 = *(const float4*)&As[p][kk][tr];
            const float2 w2 = *(const float2*)&Ws[p][kk][tc];
            acc[0][0] = fmaf(a4.x, w2.x, acc[0][0]); acc[0][1] = fmaf(a4.x, w2.y, acc[0][1]);
            acc[1][0] = fmaf(a4.y, w2.x, acc[1][0]); acc[1][1] = fmaf(a4.y, w2.y, acc[1][1]);
            acc[2][0] = fmaf(a4.z, w2.x, acc[2][0]); acc[2][1] = fmaf(a4.z, w2.y, acc[2][1]);
            acc[3][0] = fmaf(a4.w, w2.x, acc[3][0]); acc[3][1] = fmaf(a4.w, w2.y, acc[3][1]);
        }
    }
    const float2 bv = *(const float2*)(bias + c0 + tc);
#pragma unroll
    for (int i = 0; i < 4; ++i) {
        float vx = acc[i][0] + bv.x, vy = acc[i][1] + bv.y;
        if (act == 1)      { vx = silu_f(vx);     vy = silu_f(vy); }
        else if (act == 2) { vx = softplus_f(vx); vy = softplus_f(vy); }
        *(float2*)(O + (size_t)(r0 + tr + i) * ldo + c0 + tc) = make_float2(vx, vy);
    }
}

// ---- 3x3 SAME conv over (C=2, H=256, W=512), + bias + silu ----
__global__ void conv_silu_k(const float* __restrict__ xp, const float* __restrict__ cW,
                            const float* __restrict__ cb, float* __restrict__ xc) {
    int idx = blockIdx.x * blockDim.x + threadIdx.x;   // < 2*2*256*512
    int w = idx & 511;
    int l = (idx >> 9) & 255;
    int o = (idx >> 17) & 1;
    int t = idx >> 18;
    float acc = cb[o];
#pragma unroll
    for (int i = 0; i < 2; ++i) {
        const float* base = xp + (size_t)((t * 2 + i) * 256) * 512;
#pragma unroll
        for (int dh = -1; dh <= 1; ++dh) {
            int ll = l + dh;
            if (ll < 0 || ll > 255) continue;
#pragma unroll
            for (int dw = -1; dw <= 1; ++dw) {
                int ww = w + dw;
                if (ww < 0 || ww > 511) continue;
                acc += base[(size_t)ll * 512 + ww] * cW[((o * 2 + i) * 3 + (dh + 1)) * 3 + (dw + 1)];
            }
        }
    }
    xc[idx] = silu_f(acc);
}

// ---- K4: fused SSM + silu + combine + out-GEMM ----
// One block per 2 (m,l)-rows: 256 blocks x 512 threads.
// ssm[d] = sum_n Bm[n]*exp(delta[d]*A[d,n]) + xc[d]*delta[d]*sum_n Bm[n]^2
// comb[lr][d] = (silu(ssm_x)+silu(ssm_m)) * res[lr][d]; then
// out[lr][c] = comb[lr] . outW[c] + outb[c] with 16-lane-coalesced weight reads
// shared across both rows.
__global__ __launch_bounds__(512) void ssm_out_k(
        const float* __restrict__ xc, const float* __restrict__ delta,
        const float* __restrict__ Bm, const float* __restrict__ A,
        const float* __restrict__ res, const float* __restrict__ outW,
        const float* __restrict__ outb, float* __restrict__ out) {
    __shared__ float Bms[2][2][S_];    // [t][lr][n]
    __shared__ float combs[2][D2_];    // [lr][d]
    __shared__ float red[8];
    const int tid = threadIdx.x;
    const int m  = blockIdx.x >> 7;            // 0..1
    const int l0 = (blockIdx.x & 127) << 1;    // 0,2,..,254

    // stage Bm rows + per-(t,lr) sum(Bm^2)
    {
        const int g = tid >> 7;                // 0..3: t=g>>1, lr=g&1
        const int tt = g >> 1, lr = g & 1, n = tid & 127;
        const int rg = tt * 512 + m * 256 + l0 + lr;
        float bv = Bm[(size_t)rg * S_ + n];
        Bms[tt][lr][n] = bv;
        float sq = bv * bv;
        for (int off = 32; off; off >>= 1) sq += __shfl_xor(sq, off);
        if ((tid & 63) == 0) red[tid >> 6] = sq;   // s2(t,lr)=red[2g]+red[2g+1]
    }
    __syncthreads();
    // ssm for d = tid, all 4 (t,lr) combos; A[d] row read once
    {
        const int d = tid;
        float s2[2][2];
#pragma unroll
        for (int g = 0; g < 4; ++g) s2[g >> 1][g & 1] = red[2 * g] + red[2 * g + 1];
        float dl[2][2], xcv[2][2], rsv[2];
#pragma unroll
        for (int tt = 0; tt < 2; ++tt)
#pragma unroll
            for (int lr = 0; lr < 2; ++lr) {
                const size_t r = (size_t)(tt * 512 + m * 256 + l0 + lr);
                dl[tt][lr]  = delta[r * D2_ + d];
                xcv[tt][lr] = xc[r * D2_ + d];
            }
        rsv[0] = res[(size_t)(m * 256 + l0) * D2_ + d];
        rsv[1] = res[(size_t)(m * 256 + l0 + 1) * D2_ + d];
        float accs[2][2] = {};
        const float4* arow = (const float4*)(A + (size_t)d * S_);
        for (int k4 = 0; k4 < 32; ++k4) {
            float4 a4 = arow[k4];
            const int n = k4 * 4;
#pragma unroll
            for (int cmp = 0; cmp < 4; ++cmp) {
                float a = (cmp == 0) ? a4.x : (cmp == 1) ? a4.y : (cmp == 2) ? a4.z : a4.w;
#pragma unroll
                for (int tt = 0; tt < 2; ++tt)
#pragma unroll
                    for (int lr = 0; lr < 2; ++lr)
                        accs[tt][lr] += Bms[tt][lr][n + cmp] * __expf(dl[tt][lr] * a);
            }
        }
#pragma unroll
        for (int lr = 0; lr < 2; ++lr) {
            float sx = accs[0][lr] + xcv[0][lr] * dl[0][lr] * s2[0][lr];
            float sm = accs[1][lr] + xcv[1][lr] * dl[1][lr] * s2[1][lr];
            combs[lr][d] = (silu_f(sx) + silu_f(sm)) * rsv[lr];
        }
    }
    __syncthreads();
    // out: wave w covers c in [w*32, w*32+32); 4 c's per round (16 lanes each).
    // Lane j<16 reads outW[c][it*64 + j*4 .. +3] -> 256B contiguous per c-group.
    {
        const int wv = tid >> 6, lane = tid & 63;
        const int j = lane & 15, cg = lane >> 4;
#pragma unroll
        for (int rnd = 0; rnd < 8; ++rnd) {
            const int c = wv * 32 + rnd * 4 + cg;
            const float4* wrow = (const float4*)(outW + (size_t)c * D2_);
            float a0 = 0.f, a1 = 0.f;
#pragma unroll
            for (int it = 0; it < 8; ++it) {
                const int k = it * 64 + j * 4;
                float4 w4 = wrow[it * 16 + j];
                a0 += w4.x * combs[0][k] + w4.y * combs[0][k + 1]
                    + w4.z * combs[0][k + 2] + w4.w * combs[0][k + 3];
                a1 += w4.x * combs[1][k] + w4.y * combs[1][k + 1]
                    + w4.z * combs[1][k + 2] + w4.w * combs[1][k + 3];
            }
            a0 += __shfl_xor(a0, 1); a0 += __shfl_xor(a0, 2);
            a0 += __shfl_xor(a0, 4); a0 += __shfl_xor(a0, 8);
            a1 += __shfl_xor(a1, 1); a1 += __shfl_xor(a1, 2);
            a1 += __shfl_xor(a1, 4); a1 += __shfl_xor(a1, 8);
            if (j == 0) {
                const float b = outb[c];
                out[(size_t)(m * 256 + l0)     * D_ + c] = a0 + b;
                out[(size_t)(m * 256 + l0 + 1) * D_ + c] = a1 + b;
            }
        }
    }
}

extern "C" void kernel_launch(void* const* d_in, const int* in_sizes, int n_in,
                              void* d_out, int out_size, void* d_ws, size_t ws_size,
                              hipStream_t stream) {
    const float* x      = (const float*)d_in[0];
    const float* mouth  = (const float*)d_in[1];
    const float* norm_w = (const float*)d_in[2];
    const float* inp_W  = (const float*)d_in[3];
    const float* inp_b  = (const float*)d_in[4];
    const float* out_W  = (const float*)d_in[5];
    const float* out_b  = (const float*)d_in[6];
    const float* Dlin_W = (const float*)d_in[7];
    const float* Dlin_b = (const float*)d_in[8];
    const float* conv_W = (const float*)d_in[9];
    const float* conv_b = (const float*)d_in[10];
    const float* fc1_W  = (const float*)d_in[11];
    const float* fc1_b  = (const float*)d_in[12];
    const float* fc2_W  = (const float*)d_in[13];
    const float* fc2_b  = (const float*)d_in[14];
    const float* A      = (const float*)d_in[15];

    float* ws    = (float*)d_ws;
    float* xp    = ws;                        // 1024*512
    float* xc    = xp + 1024 * 512;           // 1024*512
    float* res   = xc + 1024 * 512;           // 512*512
    float* Bmb   = res + 512 * 512;           // 1024*128
    float* delta = xp;                        // alias: xp dead after conv
    float* out   = (float*)d_out;

    // K1: in-block rmsnorm + dual GEMM:
    //   xp  = xn @ inp_W^T + inp_b      (1024x512 -> 256 blocks)
    //   res = silu(xn_x @ Dlin_W^T + b) (512x512  -> 128 blocks)
    gemm_dual_k<true, 0, 1><<<384, 256, 0, stream>>>(
        x, mouth, norm_w,
        inp_W, inp_b, xp, 8, 512, 256,
        Dlin_W, Dlin_b, res, 8, 512, 256);
    // K2: xc = silu(conv3x3(xp) + cb)
    conv_silu_k<<<2048, 256, 0, stream>>>(xp, conv_W, conv_b, xc);
    // K3: dual GEMM: delta = softplus(xc@fc1_W^T+b) (1024x512 -> 256 blocks),
    //     Bm = xc@fc2_W^T+b (1024x128 -> 64 blocks); total 320.
    gemm_dual_k<false, 2, 0><<<320, 256, 0, stream>>>(
        xc, xc + (size_t)512 * 512, nullptr,
        fc1_W, fc1_b, delta, 8, 512, 256,
        fc2_W, fc2_b, Bmb, 2, 128, 512);
    // K4: ssm + combine + out GEMM (2 rows per block)
    ssm_out_k<<<256, 512, 0, stream>>>(xc, delta, Bmb, A, res,
                                       out_W, out_b, out);
}